// Round 1
// baseline (1705.028 us; speedup 1.0000x reference)
//
#include <hip/hip_runtime.h>

#define D 64          // embedding dim
#define DV 16         // float4 lanes per row (64/4)

// ---------------- kernels ----------------

__global__ void copy_f4_kernel(const float4* __restrict__ src, float4* __restrict__ dst, long n) {
    long i = (long)blockIdx.x * blockDim.x + threadIdx.x;
    long stride = (long)gridDim.x * blockDim.x;
    for (; i < n; i += stride) dst[i] = src[i];
}

__global__ void copy_i_kernel(const int* __restrict__ src, int* __restrict__ dst, int n) {
    int i = blockIdx.x * blockDim.x + threadIdx.x;
    int stride = gridDim.x * blockDim.x;
    for (; i < n; i += stride) dst[i] = src[i];
}

__global__ void hist_kernel(const int* __restrict__ eu, const int* __restrict__ ei, int E,
                            int* __restrict__ cnt_u, int* __restrict__ cnt_i) {
    int e = blockIdx.x * blockDim.x + threadIdx.x;
    int stride = gridDim.x * blockDim.x;
    for (; e < E; e += stride) {
        atomicAdd(&cnt_u[eu[e]], 1);
        atomicAdd(&cnt_i[ei[e]], 1);
    }
}

// single-block exclusive scan: rowptr[0..n] from cnt[0..n-1]
__global__ void scan_kernel(const int* __restrict__ cnt, int n, int* __restrict__ rowptr) {
    __shared__ int wsum[16];
    __shared__ int running;
    int tid = threadIdx.x;             // 1024 threads
    int lane = tid & 63, wid = tid >> 6;
    if (tid == 0) running = 0;
    __syncthreads();
    for (int base = 0; base < n; base += 1024) {
        int idx = base + tid;
        int v = (idx < n) ? cnt[idx] : 0;
        // wave-inclusive scan
        int x = v;
        #pragma unroll
        for (int d = 1; d < 64; d <<= 1) {
            int t = __shfl_up(x, d, 64);
            if (lane >= d) x += t;
        }
        if (lane == 63) wsum[wid] = x;
        __syncthreads();                       // B1: wsum ready
        if (tid < 16) {
            int y = wsum[tid];
            #pragma unroll
            for (int d = 1; d < 16; d <<= 1) {
                int t = __shfl_up(y, d, 16);
                if (tid >= d) y += t;
            }
            wsum[tid] = y;
        }
        __syncthreads();                       // B2: scanned wsum ready
        int wave_off = (wid > 0) ? wsum[wid - 1] : 0;
        int excl = wave_off + x - v;
        int r = running;
        if (idx < n) rowptr[idx] = r + excl;
        int chunk_total = wsum[15];
        __syncthreads();                       // B3: done reading running/wsum
        if (tid == 0) running += chunk_total;
        __syncthreads();                       // B4
    }
    if (tid == 0) rowptr[n] = running;
}

__global__ void scatter_kernel(const int* __restrict__ eu, const int* __restrict__ ei,
                               const float* __restrict__ ev, int E,
                               int* __restrict__ cur_u, int* __restrict__ cur_i,
                               int* __restrict__ src_u, float* __restrict__ val_u,
                               int* __restrict__ src_i, float* __restrict__ val_i) {
    int e = blockIdx.x * blockDim.x + threadIdx.x;
    int stride = gridDim.x * blockDim.x;
    for (; e < E; e += stride) {
        int u = eu[e], it = ei[e];
        float v = ev[e];
        int pi = atomicAdd(&cur_i[it], 1);     // item-destination CSR, source = user
        src_i[pi] = u;
        val_i[pi] = v;
        int pu = atomicAdd(&cur_u[u], 1);      // user-destination CSR, source = item
        src_u[pu] = it;
        val_u[pu] = v;
    }
}

// dst[row] = sum_k val[k] * src_emb[src_idx[k]]; sum_emb[row] += dst[row]
__global__ void spmm_kernel(const int* __restrict__ rowptr, const int* __restrict__ src_idx,
                            const float* __restrict__ vals, const float* __restrict__ src_emb,
                            float* __restrict__ dst_emb, float* __restrict__ sum_emb, int nrows) {
    int gid = blockIdx.x * blockDim.x + threadIdx.x;
    int row = gid >> 4;
    int lane = gid & 15;
    if (row >= nrows) return;
    int beg = rowptr[row], end = rowptr[row + 1];
    float4 acc = make_float4(0.f, 0.f, 0.f, 0.f);
    for (int k = beg; k < end; ++k) {
        int s = src_idx[k];
        float v = vals[k];
        float4 x = ((const float4*)(src_emb + (size_t)s * D))[lane];
        acc.x += v * x.x; acc.y += v * x.y; acc.z += v * x.z; acc.w += v * x.w;
    }
    ((float4*)(dst_emb + (size_t)row * D))[lane] = acc;
    float4* ps = (float4*)(sum_emb + (size_t)row * D);
    float4 sv = ps[lane];
    sv.x += acc.x; sv.y += acc.y; sv.z += acc.z; sv.w += acc.w;
    ps[lane] = sv;
}

__global__ void score_kernel(const float* __restrict__ sum_u, const float* __restrict__ sum_i,
                             const int* __restrict__ users, const int* __restrict__ items,
                             float* __restrict__ out, int B, float inv2) {
    int gid = blockIdx.x * blockDim.x + threadIdx.x;
    int b = gid >> 4;
    int lane = gid & 15;
    if (b >= B) return;
    int u = users[b], it = items[b];
    float4 a = ((const float4*)(sum_u + (size_t)u * D))[lane];
    float4 c = ((const float4*)(sum_i + (size_t)it * D))[lane];
    float d = a.x * c.x + a.y * c.y + a.z * c.z + a.w * c.w;
    #pragma unroll
    for (int m = 1; m < 16; m <<= 1) d += __shfl_xor(d, m, 64);
    if (lane == 0) out[b] = d * inv2;
}

// ---------------- launch ----------------

extern "C" void kernel_launch(void* const* d_in, const int* in_sizes, int n_in,
                              void* d_out, int out_size, void* d_ws, size_t ws_size,
                              hipStream_t stream) {
    const float* user_emb = (const float*)d_in[0];
    const float* item_emb = (const float*)d_in[1];
    const float* edge_vals = (const float*)d_in[2];
    const int* edge_u = (const int*)d_in[3];
    const int* edge_i = (const int*)d_in[4];
    const int* users = (const int*)d_in[5];
    const int* items = (const int*)d_in[6];
    float* out = (float*)d_out;

    const int U = in_sizes[0] / D;
    const int I = in_sizes[1] / D;
    const int E = in_sizes[2];
    const int B = in_sizes[5];

    // carve workspace (256B aligned)
    char* p = (char*)d_ws;
    size_t off = 0;
    auto alloc = [&](size_t bytes) -> char* {
        char* r = p + off;
        off = (off + bytes + 255) & ~(size_t)255;
        return r;
    };
    float* sum_u = (float*)alloc((size_t)U * D * 4);
    float* sum_i = (float*)alloc((size_t)I * D * 4);
    float* euA   = (float*)alloc((size_t)U * D * 4);
    float* euB   = (float*)alloc((size_t)U * D * 4);
    float* eiA   = (float*)alloc((size_t)I * D * 4);
    float* eiB   = (float*)alloc((size_t)I * D * 4);
    int* cnt_u   = (int*)alloc((size_t)(U + 1) * 4);   // also cursor
    int* cnt_i   = (int*)alloc((size_t)(I + 1) * 4);
    int* rowp_u  = (int*)alloc((size_t)(U + 1) * 4);
    int* rowp_i  = (int*)alloc((size_t)(I + 1) * 4);
    int* src_u   = (int*)alloc((size_t)E * 4);
    float* val_u = (float*)alloc((size_t)E * 4);
    int* src_i   = (int*)alloc((size_t)E * 4);
    float* val_i = (float*)alloc((size_t)E * 4);
    if (off > ws_size) return;  // workspace too small -> fail loudly (wrong output)

    const int GS = 2048;  // grid-stride blocks

    // 1. CSR build
    hipMemsetAsync(cnt_u, 0, (size_t)U * 4, stream);
    hipMemsetAsync(cnt_i, 0, (size_t)I * 4, stream);
    hist_kernel<<<GS, 256, 0, stream>>>(edge_u, edge_i, E, cnt_u, cnt_i);
    scan_kernel<<<1, 1024, 0, stream>>>(cnt_u, U, rowp_u);
    scan_kernel<<<1, 1024, 0, stream>>>(cnt_i, I, rowp_i);
    copy_i_kernel<<<256, 256, 0, stream>>>(rowp_u, cnt_u, U);  // cursors
    copy_i_kernel<<<256, 256, 0, stream>>>(rowp_i, cnt_i, I);
    scatter_kernel<<<GS, 256, 0, stream>>>(edge_u, edge_i, edge_vals, E,
                                           cnt_u, cnt_i, src_u, val_u, src_i, val_i);

    // 2. init layer sums
    copy_f4_kernel<<<GS, 256, 0, stream>>>((const float4*)user_emb, (float4*)sum_u, (long)U * DV);
    copy_f4_kernel<<<GS, 256, 0, stream>>>((const float4*)item_emb, (float4*)sum_i, (long)I * DV);

    // 3. three propagation layers (Jacobi-style: both SpMMs read the old layer)
    const float* eu_cur = user_emb;
    const float* ei_cur = item_emb;
    float* eu_nxt = euA;
    float* ei_nxt = eiA;
    for (int layer = 0; layer < 3; ++layer) {
        int blk_i = (I * DV + 255) / 256;
        int blk_u = (U * DV + 255) / 256;
        // new_i = M_ui @ e_u  (item rows gather user sources)
        spmm_kernel<<<blk_i, 256, 0, stream>>>(rowp_i, src_i, val_i, eu_cur, ei_nxt, sum_i, I);
        // new_u = M_iu @ e_i  (user rows gather item sources, OLD e_i)
        spmm_kernel<<<blk_u, 256, 0, stream>>>(rowp_u, src_u, val_u, ei_cur, eu_nxt, sum_u, U);
        eu_cur = eu_nxt; ei_cur = ei_nxt;
        eu_nxt = (eu_cur == euA) ? euB : euA;
        ei_nxt = (ei_cur == eiA) ? eiB : eiA;
    }

    // 4. final scores: inv^2 * dot(sum_u[u], sum_i[i]), inv = 1/(L+1) = 1/4
    int blk_s = (B * DV + 255) / 256;
    score_kernel<<<blk_s, 256, 0, stream>>>(sum_u, sum_i, users, items, out, B, 0.0625f);
}

// Round 2
// 793.173 us; speedup vs baseline: 2.1496x; 2.1496x over previous
//
#include <hip/hip_runtime.h>
#include <stdint.h>

#define D 64          // embedding dim
#define DV 16         // float4 lanes per row (64/4)
#define SH_I 8        // item rows per bucket = 256
#define SH_U 9        // user rows per bucket = 512
#define EPT 4         // edges per thread in passA
#define TILE 2048     // 512 threads * EPT

typedef unsigned long long u64;
typedef unsigned int u32;

// ---------------- CSR build ----------------

__global__ __launch_bounds__(512)
void init_cursors_kernel(int* cur_i, int nb_i, int cap_i,
                         int* cur_u, int nb_u, int cap_u) {
    int t = threadIdx.x;
    if (t < nb_i) cur_i[t] = t * cap_i;
    if (t < nb_u) cur_u[t] = t * cap_u;
}

// Bin edges by destination bucket for both directions in one pass.
// Record (8B): [val:32][src << SH | dst_in_bucket]
__global__ __launch_bounds__(512)
void passA_kernel(const int* __restrict__ eu, const int* __restrict__ ei,
                  const float* __restrict__ ev, int E,
                  int* __restrict__ cur_i, int nb_i,
                  int* __restrict__ cur_u, int nb_u,
                  u64* __restrict__ stg_i, u64* __restrict__ stg_u) {
    __shared__ int cnt_i[256], cnt_u[256];
    __shared__ int base_i[256], base_u[256];
    int tid = threadIdx.x;
    long tile0 = (long)blockIdx.x * TILE;
    if (tid < 256) { cnt_i[tid] = 0; cnt_u[tid] = 0; }
    __syncthreads();
    int uu[EPT], ii[EPT], lo_i[EPT], lo_u[EPT];
    float vv[EPT];
    #pragma unroll
    for (int j = 0; j < EPT; ++j) {
        long e = tile0 + tid + j * 512;
        if (e < E) {
            uu[j] = eu[e]; ii[j] = ei[e]; vv[j] = ev[e];
            lo_i[j] = atomicAdd(&cnt_i[ii[j] >> SH_I], 1);
            lo_u[j] = atomicAdd(&cnt_u[uu[j] >> SH_U], 1);
        } else {
            uu[j] = -1;
        }
    }
    __syncthreads();
    if (tid < nb_i && cnt_i[tid]) base_i[tid] = atomicAdd(&cur_i[tid], cnt_i[tid]);
    if (tid < nb_u && cnt_u[tid]) base_u[tid] = atomicAdd(&cur_u[tid], cnt_u[tid]);
    __syncthreads();
    #pragma unroll
    for (int j = 0; j < EPT; ++j) {
        if (uu[j] >= 0) {
            u64 vb = (u64)__float_as_uint(vv[j]) << 32;
            int bi = ii[j] >> SH_I;
            stg_i[base_i[bi] + lo_i[j]] =
                vb | ((u32)uu[j] << SH_I) | (u32)(ii[j] & ((1 << SH_I) - 1));
            int bu = uu[j] >> SH_U;
            stg_u[base_u[bu] + lo_u[j]] =
                vb | ((u32)ii[j] << SH_U) | (u32)(uu[j] & ((1 << SH_U) - 1));
        }
    }
}

// exclusive scan of per-bucket counts -> bucket edge bases; write rowp sentinel
__global__ __launch_bounds__(512)
void bucket_scan_kernel(const int* __restrict__ cur, int nb, int cap, int E,
                        int* __restrict__ bbase, int* __restrict__ rowp_sentinel) {
    __shared__ int wsum[8];
    int tid = threadIdx.x, lane = tid & 63, wid = tid >> 6;
    int v = (tid < nb) ? (cur[tid] - tid * cap) : 0;
    int x = v;
    #pragma unroll
    for (int d = 1; d < 64; d <<= 1) { int t = __shfl_up(x, d, 64); if (lane >= d) x += t; }
    if (lane == 63) wsum[wid] = x;
    __syncthreads();
    if (tid < 8) {
        int y = wsum[tid];
        #pragma unroll
        for (int d = 1; d < 8; d <<= 1) { int t = __shfl_up(y, d, 8); if (tid >= d) y += t; }
        wsum[tid] = y;
    }
    __syncthreads();
    int excl = ((wid > 0) ? wsum[wid - 1] : 0) + x - v;
    if (tid < nb) bbase[tid] = excl;
    if (tid == 0) *rowp_sentinel = E;
}

// Per bucket: LDS row-histogram + block scan -> rowptr; then place into final CSR.
__global__ __launch_bounds__(512)
void passB_kernel(int nb_i, int cap_i, int N_i,
                  int nb_u, int cap_u, int N_u,
                  const int* __restrict__ cur_i, const int* __restrict__ cur_u,
                  const int* __restrict__ bb_i, const int* __restrict__ bb_u,
                  const u64* __restrict__ stg_i, const u64* __restrict__ stg_u,
                  int* __restrict__ rowp_i, int* __restrict__ rowp_u,
                  int2* __restrict__ csr_i, int2* __restrict__ csr_u) {
    __shared__ int lcnt[512];
    __shared__ int wsum[8];
    int b = blockIdx.x;
    int dir_item = (b < nb_i);
    int bb = dir_item ? b : b - nb_i;
    int SH = dir_item ? SH_I : SH_U;
    int cap = dir_item ? cap_i : cap_u;
    int N = dir_item ? N_i : N_u;
    const u64* stg = dir_item ? stg_i : stg_u;
    int ebase = dir_item ? bb_i[bb] : bb_u[bb];
    int scount = (dir_item ? cur_i[bb] : cur_u[bb]) - bb * cap;
    int* rowp = dir_item ? rowp_i : rowp_u;
    int2* csr = dir_item ? csr_i : csr_u;

    int rows0 = bb << SH;
    int nrows = min(1 << SH, N - rows0);
    int sbeg = bb * cap;
    int tid = threadIdx.x;
    int mask = (1 << SH) - 1;

    lcnt[tid] = 0;
    __syncthreads();
    for (int k = tid; k < scount; k += 512) {
        int rin = (int)((u32)stg[sbeg + k] & mask);
        atomicAdd(&lcnt[rin], 1);
    }
    __syncthreads();
    // exclusive scan over lcnt[0..511]
    int lane = tid & 63, wid = tid >> 6;
    int v = lcnt[tid];
    int x = v;
    #pragma unroll
    for (int d = 1; d < 64; d <<= 1) { int t = __shfl_up(x, d, 64); if (lane >= d) x += t; }
    if (lane == 63) wsum[wid] = x;
    __syncthreads();
    if (tid < 8) {
        int y = wsum[tid];
        #pragma unroll
        for (int d = 1; d < 8; d <<= 1) { int t = __shfl_up(y, d, 8); if (tid >= d) y += t; }
        wsum[tid] = y;
    }
    __syncthreads();
    int excl = ((wid > 0) ? wsum[wid - 1] : 0) + x - v;
    lcnt[tid] = excl;                       // becomes bucket-local running cursor
    if (tid < nrows) rowp[rows0 + tid] = ebase + excl;
    __syncthreads();
    for (int k = tid; k < scount; k += 512) {
        u64 rec = stg[sbeg + k];
        int rin = (int)((u32)rec & mask);
        int src = (int)(((u32)rec) >> SH);
        int pos = ebase + atomicAdd(&lcnt[rin], 1);
        csr[pos] = make_int2(src, (int)(rec >> 32));
    }
}

// ---------------- propagation ----------------

// dst[row] = sum_k val*src_emb[src]; sum_out[row] = sum_in[row] + dst[row]
__global__ __launch_bounds__(256)
void spmm_kernel(const int* __restrict__ rowptr, const int2* __restrict__ csr,
                 const float* __restrict__ src_emb, float* __restrict__ dst_emb,
                 const float* __restrict__ sum_in, float* __restrict__ sum_out,
                 int nrows) {
    int gid = blockIdx.x * blockDim.x + threadIdx.x;
    int row = gid >> 4;
    int lane = gid & 15;
    if (row >= nrows) return;
    int beg = rowptr[row], end = rowptr[row + 1];
    float4 acc = make_float4(0.f, 0.f, 0.f, 0.f);
    int k = beg;
    for (; k + 2 <= end; k += 2) {
        int2 r0 = csr[k], r1 = csr[k + 1];
        float4 x0 = ((const float4*)(src_emb + (size_t)r0.x * D))[lane];
        float4 x1 = ((const float4*)(src_emb + (size_t)r1.x * D))[lane];
        float v0 = __int_as_float(r0.y), v1 = __int_as_float(r1.y);
        acc.x += v0 * x0.x; acc.y += v0 * x0.y; acc.z += v0 * x0.z; acc.w += v0 * x0.w;
        acc.x += v1 * x1.x; acc.y += v1 * x1.y; acc.z += v1 * x1.z; acc.w += v1 * x1.w;
    }
    if (k < end) {
        int2 r0 = csr[k];
        float4 x0 = ((const float4*)(src_emb + (size_t)r0.x * D))[lane];
        float v0 = __int_as_float(r0.y);
        acc.x += v0 * x0.x; acc.y += v0 * x0.y; acc.z += v0 * x0.z; acc.w += v0 * x0.w;
    }
    ((float4*)(dst_emb + (size_t)row * D))[lane] = acc;
    float4 s = ((const float4*)(sum_in + (size_t)row * D))[lane];
    s.x += acc.x; s.y += acc.y; s.z += acc.z; s.w += acc.w;
    ((float4*)(sum_out + (size_t)row * D))[lane] = s;
}

__global__ __launch_bounds__(256)
void score_kernel(const float* __restrict__ sum_u, const float* __restrict__ sum_i,
                  const int* __restrict__ users, const int* __restrict__ items,
                  float* __restrict__ out, int B, float inv2) {
    int gid = blockIdx.x * blockDim.x + threadIdx.x;
    int b = gid >> 4;
    int lane = gid & 15;
    if (b >= B) return;
    int u = users[b], it = items[b];
    float4 a = ((const float4*)(sum_u + (size_t)u * D))[lane];
    float4 c = ((const float4*)(sum_i + (size_t)it * D))[lane];
    float d = a.x * c.x + a.y * c.y + a.z * c.z + a.w * c.w;
    #pragma unroll
    for (int m = 1; m < 16; m <<= 1) d += __shfl_xor(d, m, 64);
    if (lane == 0) out[b] = d * inv2;
}

// ---------------- launch ----------------

extern "C" void kernel_launch(void* const* d_in, const int* in_sizes, int n_in,
                              void* d_out, int out_size, void* d_ws, size_t ws_size,
                              hipStream_t stream) {
    const float* user_emb = (const float*)d_in[0];
    const float* item_emb = (const float*)d_in[1];
    const float* edge_vals = (const float*)d_in[2];
    const int* edge_u = (const int*)d_in[3];
    const int* edge_i = (const int*)d_in[4];
    const int* users = (const int*)d_in[5];
    const int* items = (const int*)d_in[6];
    float* out = (float*)d_out;

    const int U = in_sizes[0] / D;
    const int I = in_sizes[1] / D;
    const int E = in_sizes[2];
    const int B = in_sizes[5];

    const int nb_i = (I + (1 << SH_I) - 1) >> SH_I;   // 196
    const int nb_u = (U + (1 << SH_U) - 1) >> SH_U;   // 196
    const int cap_i = ((E / nb_i + E / (8 * nb_i) + 1024 + 63) / 64) * 64;
    const int cap_u = ((E / nb_u + E / (8 * nb_u) + 1024 + 63) / 64) * 64;

    // carve workspace (256B aligned)
    char* p = (char*)d_ws;
    size_t off = 0;
    auto alloc = [&](size_t bytes) -> char* {
        char* r = p + off;
        off = (off + bytes + 255) & ~(size_t)255;
        return r;
    };
    float* sum_u = (float*)alloc((size_t)U * D * 4);
    float* sum_i = (float*)alloc((size_t)I * D * 4);
    float* euA   = (float*)alloc((size_t)U * D * 4);
    float* eiA   = (float*)alloc((size_t)I * D * 4);
    int2* csr_u  = (int2*)alloc((size_t)E * 8);
    int2* csr_i  = (int2*)alloc((size_t)E * 8);
    int* rowp_u  = (int*)alloc((size_t)(U + 1) * 4);
    int* rowp_i  = (int*)alloc((size_t)(I + 1) * 4);
    int* cur_i   = (int*)alloc((size_t)nb_i * 4);
    int* cur_u   = (int*)alloc((size_t)nb_u * 4);
    int* bb_i    = (int*)alloc((size_t)nb_i * 4);
    int* bb_u    = (int*)alloc((size_t)nb_u * 4);
    u64* stg_i   = (u64*)alloc((size_t)nb_i * cap_i * 8);
    u64* stg_u   = (u64*)alloc((size_t)nb_u * cap_u * 8);
    // stg_* are dead after passB: alias the layer ping-pong buffers over them
    float* euB = (float*)stg_i;   // needs U*D*4 = 25.6MB <= 27.8MB
    float* eiB = (float*)stg_u;   // needs I*D*4 = 12.8MB
    if (off > ws_size) return;    // workspace too small -> fail loudly

    // 1. CSR build (both directions)
    init_cursors_kernel<<<1, 512, 0, stream>>>(cur_i, nb_i, cap_i, cur_u, nb_u, cap_u);
    int tiles = (int)((E + TILE - 1) / TILE);
    passA_kernel<<<tiles, 512, 0, stream>>>(edge_u, edge_i, edge_vals, E,
                                            cur_i, nb_i, cur_u, nb_u, stg_i, stg_u);
    bucket_scan_kernel<<<1, 512, 0, stream>>>(cur_i, nb_i, cap_i, E, bb_i, rowp_i + I);
    bucket_scan_kernel<<<1, 512, 0, stream>>>(cur_u, nb_u, cap_u, E, bb_u, rowp_u + U);
    passB_kernel<<<nb_i + nb_u, 512, 0, stream>>>(nb_i, cap_i, I, nb_u, cap_u, U,
                                                  cur_i, cur_u, bb_i, bb_u,
                                                  stg_i, stg_u, rowp_i, rowp_u,
                                                  csr_i, csr_u);

    // 2. three propagation layers (Jacobi: both SpMMs read the old layer)
    int blk_i = (I * DV + 255) / 256;
    int blk_u = (U * DV + 255) / 256;
    // layer 0 (sum_in = original embeddings -> fuses the sum init)
    spmm_kernel<<<blk_i, 256, 0, stream>>>(rowp_i, csr_i, user_emb, eiA, item_emb, sum_i, I);
    spmm_kernel<<<blk_u, 256, 0, stream>>>(rowp_u, csr_u, item_emb, euA, user_emb, sum_u, U);
    // layer 1
    spmm_kernel<<<blk_i, 256, 0, stream>>>(rowp_i, csr_i, euA, eiB, sum_i, sum_i, I);
    spmm_kernel<<<blk_u, 256, 0, stream>>>(rowp_u, csr_u, eiA, euB, sum_u, sum_u, U);
    // layer 2
    spmm_kernel<<<blk_i, 256, 0, stream>>>(rowp_i, csr_i, euB, eiA, sum_i, sum_i, I);
    spmm_kernel<<<blk_u, 256, 0, stream>>>(rowp_u, csr_u, eiB, euA, sum_u, sum_u, U);

    // 3. final scores: inv^2 * dot(sum_u[u], sum_i[i]), inv = 1/(L+1) = 1/4
    int blk_s = (B * DV + 255) / 256;
    score_kernel<<<blk_s, 256, 0, stream>>>(sum_u, sum_i, users, items, out, B, 0.0625f);
}

// Round 3
// 741.050 us; speedup vs baseline: 2.3008x; 1.0703x over previous
//
#include <hip/hip_runtime.h>
#include <stdint.h>

#define D 64          // embedding dim
#define DV 16         // float4 lanes per row (64/4)
#define SH_I 8        // item rows per bucket = 256
#define SH_U 9        // user rows per bucket = 512
#define EPT 4         // edges per thread in passA
#define TILE 2048     // 512 threads * EPT

typedef unsigned long long u64;
typedef unsigned int u32;

// ---------------- CSR build ----------------

__global__ __launch_bounds__(512)
void init_cursors_kernel(int* cur_i, int nb_i, int cap_i,
                         int* cur_u, int nb_u, int cap_u) {
    int t = threadIdx.x;
    if (t < nb_i) cur_i[t] = t * cap_i;
    if (t < nb_u) cur_u[t] = t * cap_u;
}

// Bin edges by destination bucket for both directions in one pass.
// Record (8B): [val:32][src << SH | dst_in_bucket]
__global__ __launch_bounds__(512)
void passA_kernel(const int* __restrict__ eu, const int* __restrict__ ei,
                  const float* __restrict__ ev, int E,
                  int* __restrict__ cur_i, int nb_i,
                  int* __restrict__ cur_u, int nb_u,
                  u64* __restrict__ stg_i, u64* __restrict__ stg_u) {
    __shared__ int cnt_i[256], cnt_u[256];
    __shared__ int base_i[256], base_u[256];
    int tid = threadIdx.x;
    long tile0 = (long)blockIdx.x * TILE;
    if (tid < 256) { cnt_i[tid] = 0; cnt_u[tid] = 0; }
    __syncthreads();
    int uu[EPT], ii[EPT], lo_i[EPT], lo_u[EPT];
    float vv[EPT];
    #pragma unroll
    for (int j = 0; j < EPT; ++j) {
        long e = tile0 + tid + j * 512;
        if (e < E) {
            uu[j] = eu[e]; ii[j] = ei[e]; vv[j] = ev[e];
            lo_i[j] = atomicAdd(&cnt_i[ii[j] >> SH_I], 1);
            lo_u[j] = atomicAdd(&cnt_u[uu[j] >> SH_U], 1);
        } else {
            uu[j] = -1;
        }
    }
    __syncthreads();
    if (tid < nb_i && cnt_i[tid]) base_i[tid] = atomicAdd(&cur_i[tid], cnt_i[tid]);
    if (tid < nb_u && cnt_u[tid]) base_u[tid] = atomicAdd(&cur_u[tid], cnt_u[tid]);
    __syncthreads();
    #pragma unroll
    for (int j = 0; j < EPT; ++j) {
        if (uu[j] >= 0) {
            u64 vb = (u64)__float_as_uint(vv[j]) << 32;
            int bi = ii[j] >> SH_I;
            stg_i[base_i[bi] + lo_i[j]] =
                vb | ((u32)uu[j] << SH_I) | (u32)(ii[j] & ((1 << SH_I) - 1));
            int bu = uu[j] >> SH_U;
            stg_u[base_u[bu] + lo_u[j]] =
                vb | ((u32)ii[j] << SH_U) | (u32)(uu[j] & ((1 << SH_U) - 1));
        }
    }
}

// exclusive scan of per-bucket counts -> bucket edge bases; write rowp sentinel
__global__ __launch_bounds__(512)
void bucket_scan_kernel(const int* __restrict__ cur, int nb, int cap, int E,
                        int* __restrict__ bbase, int* __restrict__ rowp_sentinel) {
    __shared__ int wsum[8];
    int tid = threadIdx.x, lane = tid & 63, wid = tid >> 6;
    int v = (tid < nb) ? (cur[tid] - tid * cap) : 0;
    int x = v;
    #pragma unroll
    for (int d = 1; d < 64; d <<= 1) { int t = __shfl_up(x, d, 64); if (lane >= d) x += t; }
    if (lane == 63) wsum[wid] = x;
    __syncthreads();
    if (tid < 8) {
        int y = wsum[tid];
        #pragma unroll
        for (int d = 1; d < 8; d <<= 1) { int t = __shfl_up(y, d, 8); if (tid >= d) y += t; }
        wsum[tid] = y;
    }
    __syncthreads();
    int excl = ((wid > 0) ? wsum[wid - 1] : 0) + x - v;
    if (tid < nb) bbase[tid] = excl;
    if (tid == 0) *rowp_sentinel = E;
}

// Per bucket: LDS row-histogram + block scan -> rowptr; then place into final CSR.
__global__ __launch_bounds__(512)
void passB_kernel(int nb_i, int cap_i, int N_i,
                  int nb_u, int cap_u, int N_u,
                  const int* __restrict__ cur_i, const int* __restrict__ cur_u,
                  const int* __restrict__ bb_i, const int* __restrict__ bb_u,
                  const u64* __restrict__ stg_i, const u64* __restrict__ stg_u,
                  int* __restrict__ rowp_i, int* __restrict__ rowp_u,
                  int2* __restrict__ csr_i, int2* __restrict__ csr_u) {
    __shared__ int lcnt[512];
    __shared__ int wsum[8];
    int b = blockIdx.x;
    int dir_item = (b < nb_i);
    int bb = dir_item ? b : b - nb_i;
    int SH = dir_item ? SH_I : SH_U;
    int cap = dir_item ? cap_i : cap_u;
    int N = dir_item ? N_i : N_u;
    const u64* stg = dir_item ? stg_i : stg_u;
    int ebase = dir_item ? bb_i[bb] : bb_u[bb];
    int scount = (dir_item ? cur_i[bb] : cur_u[bb]) - bb * cap;
    int* rowp = dir_item ? rowp_i : rowp_u;
    int2* csr = dir_item ? csr_i : csr_u;

    int rows0 = bb << SH;
    int nrows = min(1 << SH, N - rows0);
    int sbeg = bb * cap;
    int tid = threadIdx.x;
    int mask = (1 << SH) - 1;

    lcnt[tid] = 0;
    __syncthreads();
    for (int k = tid; k < scount; k += 512) {
        int rin = (int)((u32)stg[sbeg + k] & mask);
        atomicAdd(&lcnt[rin], 1);
    }
    __syncthreads();
    // exclusive scan over lcnt[0..511]
    int lane = tid & 63, wid = tid >> 6;
    int v = lcnt[tid];
    int x = v;
    #pragma unroll
    for (int d = 1; d < 64; d <<= 1) { int t = __shfl_up(x, d, 64); if (lane >= d) x += t; }
    if (lane == 63) wsum[wid] = x;
    __syncthreads();
    if (tid < 8) {
        int y = wsum[tid];
        #pragma unroll
        for (int d = 1; d < 8; d <<= 1) { int t = __shfl_up(y, d, 8); if (tid >= d) y += t; }
        wsum[tid] = y;
    }
    __syncthreads();
    int excl = ((wid > 0) ? wsum[wid - 1] : 0) + x - v;
    lcnt[tid] = excl;                       // becomes bucket-local running cursor
    if (tid < nrows) rowp[rows0 + tid] = ebase + excl;
    __syncthreads();
    for (int k = tid; k < scount; k += 512) {
        u64 rec = stg[sbeg + k];
        int rin = (int)((u32)rec & mask);
        int src = (int)(((u32)rec) >> SH);
        int pos = ebase + atomicAdd(&lcnt[rin], 1);
        csr[pos] = make_int2(src, (int)(rec >> 32));
    }
}

// ---------------- propagation ----------------

// Wave-per-row SpMM, 16 edges in flight per wave.
// lane = (g:2 | el:4): subgroup g in 0..3 handles edges k+g, k+g+4, k+g+8, k+g+12;
// el indexes the row's float4 elements. Masked tail (src->0, val->0).
// dst[row] = sum_k val*src_emb[src]; sum_out[row] = sum_in[row] + dst[row]
__global__ __launch_bounds__(256)
void spmm_kernel(const int* __restrict__ rowptr, const int2* __restrict__ csr,
                 const float* __restrict__ src_emb, float* __restrict__ dst_emb,
                 const float* __restrict__ sum_in, float* __restrict__ sum_out,
                 int nrows) {
    int row = blockIdx.x * 4 + (threadIdx.x >> 6);
    if (row >= nrows) return;
    int lane = threadIdx.x & 63;
    int g = lane >> 4;
    int el = lane & 15;
    int beg = rowptr[row], end = rowptr[row + 1];
    const float4* sb = (const float4*)src_emb + el;
    float4 A0 = {0,0,0,0}, A1 = {0,0,0,0}, A2 = {0,0,0,0}, A3 = {0,0,0,0};
    for (int k = beg + g; k < end; k += 16) {
        int2 r0 = csr[k];
        int2 r1 = csr[k + 4];
        int2 r2 = csr[k + 8];
        int2 r3 = csr[k + 12];
        bool m1 = (k + 4) < end, m2 = (k + 8) < end, m3 = (k + 12) < end;
        int s0 = r0.x;
        int s1 = m1 ? r1.x : 0;
        int s2 = m2 ? r2.x : 0;
        int s3 = m3 ? r3.x : 0;
        float v0 = __int_as_float(r0.y);
        float v1 = m1 ? __int_as_float(r1.y) : 0.f;
        float v2 = m2 ? __int_as_float(r2.y) : 0.f;
        float v3 = m3 ? __int_as_float(r3.y) : 0.f;
        float4 x0 = sb[(size_t)s0 * DV];
        float4 x1 = sb[(size_t)s1 * DV];
        float4 x2 = sb[(size_t)s2 * DV];
        float4 x3 = sb[(size_t)s3 * DV];
        A0.x += v0 * x0.x; A0.y += v0 * x0.y; A0.z += v0 * x0.z; A0.w += v0 * x0.w;
        A1.x += v1 * x1.x; A1.y += v1 * x1.y; A1.z += v1 * x1.z; A1.w += v1 * x1.w;
        A2.x += v2 * x2.x; A2.y += v2 * x2.y; A2.z += v2 * x2.z; A2.w += v2 * x2.w;
        A3.x += v3 * x3.x; A3.y += v3 * x3.y; A3.z += v3 * x3.z; A3.w += v3 * x3.w;
    }
    float4 a;
    a.x = (A0.x + A1.x) + (A2.x + A3.x);
    a.y = (A0.y + A1.y) + (A2.y + A3.y);
    a.z = (A0.z + A1.z) + (A2.z + A3.z);
    a.w = (A0.w + A1.w) + (A2.w + A3.w);
    a.x += __shfl_xor(a.x, 16, 64); a.x += __shfl_xor(a.x, 32, 64);
    a.y += __shfl_xor(a.y, 16, 64); a.y += __shfl_xor(a.y, 32, 64);
    a.z += __shfl_xor(a.z, 16, 64); a.z += __shfl_xor(a.z, 32, 64);
    a.w += __shfl_xor(a.w, 16, 64); a.w += __shfl_xor(a.w, 32, 64);
    if (g == 0) {
        ((float4*)(dst_emb + (size_t)row * D))[el] = a;
        float4 s = ((const float4*)(sum_in + (size_t)row * D))[el];
        s.x += a.x; s.y += a.y; s.z += a.z; s.w += a.w;
        ((float4*)(sum_out + (size_t)row * D))[el] = s;
    }
}

__global__ __launch_bounds__(256)
void score_kernel(const float* __restrict__ sum_u, const float* __restrict__ sum_i,
                  const int* __restrict__ users, const int* __restrict__ items,
                  float* __restrict__ out, int B, float inv2) {
    int gid = blockIdx.x * blockDim.x + threadIdx.x;
    int b = gid >> 4;
    int lane = gid & 15;
    if (b >= B) return;
    int u = users[b], it = items[b];
    float4 a = ((const float4*)(sum_u + (size_t)u * D))[lane];
    float4 c = ((const float4*)(sum_i + (size_t)it * D))[lane];
    float d = a.x * c.x + a.y * c.y + a.z * c.z + a.w * c.w;
    #pragma unroll
    for (int m = 1; m < 16; m <<= 1) d += __shfl_xor(d, m, 64);
    if (lane == 0) out[b] = d * inv2;
}

// ---------------- launch ----------------

extern "C" void kernel_launch(void* const* d_in, const int* in_sizes, int n_in,
                              void* d_out, int out_size, void* d_ws, size_t ws_size,
                              hipStream_t stream) {
    const float* user_emb = (const float*)d_in[0];
    const float* item_emb = (const float*)d_in[1];
    const float* edge_vals = (const float*)d_in[2];
    const int* edge_u = (const int*)d_in[3];
    const int* edge_i = (const int*)d_in[4];
    const int* users = (const int*)d_in[5];
    const int* items = (const int*)d_in[6];
    float* out = (float*)d_out;

    const int U = in_sizes[0] / D;
    const int I = in_sizes[1] / D;
    const int E = in_sizes[2];
    const int B = in_sizes[5];

    const int nb_i = (I + (1 << SH_I) - 1) >> SH_I;   // 196
    const int nb_u = (U + (1 << SH_U) - 1) >> SH_U;   // 196
    const int cap_i = ((E / nb_i + E / (8 * nb_i) + 1024 + 63) / 64) * 64;
    const int cap_u = ((E / nb_u + E / (8 * nb_u) + 1024 + 63) / 64) * 64;

    // carve workspace (256B aligned)
    char* p = (char*)d_ws;
    size_t off = 0;
    auto alloc = [&](size_t bytes) -> char* {
        char* r = p + off;
        off = (off + bytes + 255) & ~(size_t)255;
        return r;
    };
    float* sum_u = (float*)alloc((size_t)U * D * 4);
    float* sum_i = (float*)alloc((size_t)I * D * 4);
    float* euA   = (float*)alloc((size_t)U * D * 4);
    float* eiA   = (float*)alloc((size_t)I * D * 4);
    int2* csr_u  = (int2*)alloc((size_t)(E + 16) * 8);  // +16: masked tail over-reads
    int2* csr_i  = (int2*)alloc((size_t)(E + 16) * 8);
    int* rowp_u  = (int*)alloc((size_t)(U + 1) * 4);
    int* rowp_i  = (int*)alloc((size_t)(I + 1) * 4);
    int* cur_i   = (int*)alloc((size_t)nb_i * 4);
    int* cur_u   = (int*)alloc((size_t)nb_u * 4);
    int* bb_i    = (int*)alloc((size_t)nb_i * 4);
    int* bb_u    = (int*)alloc((size_t)nb_u * 4);
    u64* stg_i   = (u64*)alloc((size_t)nb_i * cap_i * 8);
    u64* stg_u   = (u64*)alloc((size_t)nb_u * cap_u * 8);
    // stg_* are dead after passB: alias the layer ping-pong buffers over them
    float* euB = (float*)stg_i;   // needs U*D*4 = 25.6MB <= 27.8MB
    float* eiB = (float*)stg_u;   // needs I*D*4 = 12.8MB
    if (off > ws_size) return;    // workspace too small -> fail loudly

    // 1. CSR build (both directions)
    init_cursors_kernel<<<1, 512, 0, stream>>>(cur_i, nb_i, cap_i, cur_u, nb_u, cap_u);
    int tiles = (int)((E + TILE - 1) / TILE);
    passA_kernel<<<tiles, 512, 0, stream>>>(edge_u, edge_i, edge_vals, E,
                                            cur_i, nb_i, cur_u, nb_u, stg_i, stg_u);
    bucket_scan_kernel<<<1, 512, 0, stream>>>(cur_i, nb_i, cap_i, E, bb_i, rowp_i + I);
    bucket_scan_kernel<<<1, 512, 0, stream>>>(cur_u, nb_u, cap_u, E, bb_u, rowp_u + U);
    passB_kernel<<<nb_i + nb_u, 512, 0, stream>>>(nb_i, cap_i, I, nb_u, cap_u, U,
                                                  cur_i, cur_u, bb_i, bb_u,
                                                  stg_i, stg_u, rowp_i, rowp_u,
                                                  csr_i, csr_u);

    // 2. three propagation layers (Jacobi: both SpMMs read the old layer)
    int blk_i = (I + 3) / 4;
    int blk_u = (U + 3) / 4;
    // layer 0 (sum_in = original embeddings -> fuses the sum init)
    spmm_kernel<<<blk_i, 256, 0, stream>>>(rowp_i, csr_i, user_emb, eiA, item_emb, sum_i, I);
    spmm_kernel<<<blk_u, 256, 0, stream>>>(rowp_u, csr_u, item_emb, euA, user_emb, sum_u, U);
    // layer 1
    spmm_kernel<<<blk_i, 256, 0, stream>>>(rowp_i, csr_i, euA, eiB, sum_i, sum_i, I);
    spmm_kernel<<<blk_u, 256, 0, stream>>>(rowp_u, csr_u, eiA, euB, sum_u, sum_u, U);
    // layer 2
    spmm_kernel<<<blk_i, 256, 0, stream>>>(rowp_i, csr_i, euB, eiA, sum_i, sum_i, I);
    spmm_kernel<<<blk_u, 256, 0, stream>>>(rowp_u, csr_u, eiB, euA, sum_u, sum_u, U);

    // 3. final scores: inv^2 * dot(sum_u[u], sum_i[i]), inv = 1/(L+1) = 1/4
    int blk_s = (B * DV + 255) / 256;
    score_kernel<<<blk_s, 256, 0, stream>>>(sum_u, sum_i, users, items, out, B, 0.0625f);
}